// Round 7
// baseline (73.929 us; speedup 1.0000x reference)
//
#include <hip/hip_runtime.h>
#include <math.h>

#define KC 3
#define HH 480
#define WW 640
#define HWPIX (HH * WW)
#define FSTRIDE (HWPIX * 3)   // floats per frame plane

typedef float v2f __attribute__((ext_vector_type(2)));

__device__ __forceinline__ float frcp(float x) { return __builtin_amdgcn_rcpf(x); }
__device__ __forceinline__ float fexp2(float x) { return __builtin_amdgcn_exp2f(x); }
__device__ __forceinline__ v2f exp2v(v2f x) { return (v2f){fexp2(x.x), fexp2(x.y)}; }
__device__ __forceinline__ v2f v2(float s) { return (v2f){s, s}; }

// x + (x from lane^1)  — full-rate VALU DPP, no LDS. 0xB1 = quad_perm[1,0,3,2]
__device__ __forceinline__ float dpp_pair_sum(float x) {
    int v = __builtin_amdgcn_update_dpp(0, __float_as_int(x), 0xB1, 0xF, 0xF, true);
    return x + __int_as_float(v);
}

__global__ __launch_bounds__(64, 8) void gmm_fit_process_kernel(
    const float* __restrict__ frames,   // [N,H,W,3]
    const float* __restrict__ frame,    // [H,W,3]
    const int* __restrict__ n_iter_p,
    float* __restrict__ out)            // [2,H,W]
{
    const int t = blockIdx.x * 64 + threadIdx.x;   // 0 .. 614399
    const int p = t >> 1;                          // pixel (2 threads per pixel)
    const int h = t & 1;                           // sample-half: samples 4h..4h+3
    const int n_iter = *n_iter_p;

    // ---- scalar per-pixel GMM state (identical on both lanes of a pair) ----
    float mean[KC][3], dev[KC], weight[KC];
#pragma unroll
    for (int k = 0; k < KC; ++k) {
        const float m0 = (float)(k + 1) / 4.0f;
        mean[k][0] = m0; mean[k][1] = m0; mean[k][2] = m0;
        dev[k] = 1.0f;
        weight[k] = 1.0f / 3.0f;
    }

    const float L2E = 1.4426950408889634f;   // log2(e)
    const float DEV_FLOOR = 1e-12f;
    const float S_FLOOR = 1e-20f;

    const float* my_base = frames + (size_t)(4 * h) * FSTRIDE + (size_t)p * 3;

    for (int it = 0; it < n_iter; ++it) {
        // per-component constants (scalar). Base-2 exponent: e = A*(||X||^2 - 2 dot + ||m||^2)
        // NOTE: 1/sqrt((2pi)^3) dropped from cc — common factor cancels in the softmax.
        float A[KC], B[KC], cc[KC];
#pragma unroll
        for (int k = 0; k < KC; ++k) {
            const float invd = frcp(fmaxf(dev[k], DEV_FLOOR));
            const float a2 = -0.5f * L2E * invd * invd;
            const float m2 = mean[k][0] * mean[k][0] + mean[k][1] * mean[k][1]
                           + mean[k][2] * mean[k][2];
            A[k] = a2;
            B[k] = a2 * m2;                 // e = A*(q - 2t) + B
            cc[k] = weight[k] * invd;
        }

        float rs[KC], mx[KC], my[KC], mz[KC], ac2[KC];
#pragma unroll
        for (int k = 0; k < KC; ++k) { rs[k] = mx[k] = my[k] = mz[k] = ac2[k] = 0.0f; }

        // two sample-PAIRS per thread, loaded from L2 each iteration (keeps VGPR <= 64)
#pragma unroll
        for (int j = 0; j < 2; ++j) {
            const float* a = my_base + (size_t)(2 * j) * FSTRIDE;
            const float* b = a + FSTRIDE;
            const v2f x0 = (v2f){a[0], b[0]};
            const v2f x1 = (v2f){a[1], b[1]};
            const v2f x2 = (v2f){a[2], b[2]};
            const v2f q = x0 * x0 + x1 * x1 + x2 * x2;   // ||X||^2

            v2f r[KC], s = v2(0.0f);
#pragma unroll
            for (int k = 0; k < KC; ++k) {
                const v2f td = v2(mean[k][0]) * x0 + v2(mean[k][1]) * x1
                             + v2(mean[k][2]) * x2;
                const v2f u = q - v2(2.0f) * td;          // fma
                const v2f e = v2(A[k]) * u + v2(B[k]);    // fma
                r[k] = v2(cc[k]) * exp2v(e);
                s += r[k];
            }
            const v2f sinv = (v2f){ (s.x > S_FLOOR) ? frcp(s.x) : 0.0f,
                                    (s.y > S_FLOOR) ? frcp(s.y) : 0.0f };
#pragma unroll
            for (int k = 0; k < KC; ++k) {
                const v2f rk = r[k] * sinv;
                const v2f c0 = rk * x0;
                const v2f c1 = rk * x1;
                const v2f c2 = rk * x2;
                const v2f cq = rk * q;
                rs[k]  += rk.x;  rs[k]  += rk.y;
                mx[k]  += c0.x;  mx[k]  += c0.y;
                my[k]  += c1.x;  my[k]  += c1.y;
                mz[k]  += c2.x;  mz[k]  += c2.y;
                ac2[k] += cq.x;  ac2[k] += cq.y;
            }
        }

        // cross-lane pair reduction: after this, BOTH lanes hold the full 8-sample sums
#pragma unroll
        for (int k = 0; k < KC; ++k) {
            rs[k]  = dpp_pair_sum(rs[k]);
            mx[k]  = dpp_pair_sum(mx[k]);
            my[k]  = dpp_pair_sum(my[k]);
            mz[k]  = dpp_pair_sum(mz[k]);
            ac2[k] = dpp_pair_sum(ac2[k]);
        }

        // scalar M-step finalize (identical on both lanes)
#pragma unroll
        for (int k = 0; k < KC; ++k) {
            const float invrs = frcp(rs[k]);          // garbage if starved; selected away
            const float nm0 = mx[k] * invrs, nm1 = my[k] * invrs, nm2 = mz[k] * invrs;
            const float mm2 = nm0 * nm0 + nm1 * nm1 + nm2 * nm2;
            const float ndev = ac2[k] * invrs - mm2;  // Koenig identity
            const bool ok = rs[k] > S_FLOOR;
            mean[k][0] = ok ? nm0 : mean[k][0];
            mean[k][1] = ok ? nm1 : mean[k][1];
            mean[k][2] = ok ? nm2 : mean[k][2];
            dev[k]     = ok ? ndev : dev[k];
            weight[k]  = rs[k] * 0.125f;              // rs/N — reference semantics
        }
    }

    // ---- fg ratio ----
    float ratio[KC];
    float rmin = 3.402823466e+38f;
#pragma unroll
    for (int k = 0; k < KC; ++k) {
        ratio[k] = weight[k] * frcp(fmaxf(dev[k], DEV_FLOOR));
        rmin = fminf(rmin, ratio[k]);
    }

    // ---- process the single test frame (both lanes of a pair redundantly) ----
    const float* fr = frame + (size_t)p * 3;
    const float fx = fr[0], fy = fr[1], fz = fr[2];

    float mind = 3.402823466e+38f;
    int index = 0;
#pragma unroll
    for (int k = 0; k < KC; ++k) {
        const float dx = fx - mean[k][0];
        const float dy = fy - mean[k][1];
        const float dz = fz - mean[k][2];
        const float dist = __builtin_amdgcn_sqrtf(dx * dx + dy * dy + dz * dz);
        if (dist < mind) { mind = dist; index = k; }  // first-min (jnp.argmin)
    }

    const float mask = (ratio[index] <= rmin) ? 255.0f : 0.0f;
    const float md = isfinite(mind) ? mind : 0.0f;

    // parity store: even lane -> mask plane, odd lane -> min_dist plane
    const float val = h ? md : mask;
    out[(size_t)h * HWPIX + p] = val;
}

extern "C" void kernel_launch(void* const* d_in, const int* in_sizes, int n_in,
                              void* d_out, int out_size, void* d_ws, size_t ws_size,
                              hipStream_t stream) {
    const float* frames = (const float*)d_in[0];
    const float* frame  = (const float*)d_in[1];
    const int*   n_iter = (const int*)d_in[2];
    float* out = (float*)d_out;

    const int threads = 64;
    const int blocks = (HWPIX * 2) / threads;   // 9600 full waves, no partial blocks
    gmm_fit_process_kernel<<<blocks, threads, 0, stream>>>(frames, frame, n_iter, out);
}

// Round 8
// 33.089 us; speedup vs baseline: 2.2343x; 2.2343x over previous
//
#include <hip/hip_runtime.h>
#include <math.h>

#define KC 3
#define HH 480
#define WW 640
#define HWPIX (HH * WW)
#define FSTRIDE (HWPIX * 3)   // floats per frame plane

__device__ __forceinline__ float frcp(float x) { return __builtin_amdgcn_rcpf(x); }
__device__ __forceinline__ float fexp2(float x) { return __builtin_amdgcn_exp2f(x); }

// x + (x from lane^1) — full-rate VALU DPP (quad_perm[1,0,3,2]); both lanes get the sum
__device__ __forceinline__ float dpp_pair_sum(float x) {
    int v = __builtin_amdgcn_update_dpp(0, __float_as_int(x), 0xB1, 0xF, 0xF, true);
    return x + __int_as_float(v);
}

__global__ __launch_bounds__(64, 4) void gmm_fit_process_kernel(
    const float* __restrict__ frames,   // [N,H,W,3]
    const float* __restrict__ frame,    // [H,W,3]
    const int* __restrict__ n_iter_p,
    float* __restrict__ out)            // [2,H,W]
{
    const int t = blockIdx.x * 64 + threadIdx.x;   // 0 .. 2*HWPIX-1
    const int p = t >> 1;                          // pixel (2 threads per pixel)
    const int h = t & 1;                           // this thread owns samples 4h..4h+3
    const int n_iter = *n_iter_p;

    // ---- load this thread's 4 samples ONCE into registers ----
    float x0[4], x1[4], x2[4], q[4];
    {
        const float* base = frames + (size_t)(4 * h) * FSTRIDE + (size_t)p * 3;
#pragma unroll
        for (int j = 0; j < 4; ++j) {
            const float* s = base + (size_t)j * FSTRIDE;
            x0[j] = s[0]; x1[j] = s[1]; x2[j] = s[2];
            q[j] = x0[j] * x0[j] + x1[j] * x1[j] + x2[j] * x2[j];
        }
    }

    // ---- scalar per-pixel GMM state (identical on both lanes of a pair) ----
    float mean0[KC], mean1[KC], mean2[KC], dev[KC], weight[KC];
#pragma unroll
    for (int k = 0; k < KC; ++k) {
        const float m0 = (float)(k + 1) / 4.0f;
        mean0[k] = m0; mean1[k] = m0; mean2[k] = m0;
        dev[k] = 1.0f;
        weight[k] = 1.0f / 3.0f;
    }

    const float L2E = 1.4426950408889634f;   // log2(e)
    const float DEV_FLOOR = 1e-12f;
    const float S_FLOOR = 1e-20f;

    for (int it = 0; it < n_iter; ++it) {
        // per-component constants. Base-2 exponent: e = A*(q - 2*dot) + B
        // 1/sqrt((2pi)^3) dropped — common factor cancels in the per-sample softmax.
        float A[KC], B[KC], cc[KC];
#pragma unroll
        for (int k = 0; k < KC; ++k) {
            const float invd = frcp(fmaxf(dev[k], DEV_FLOOR));
            const float a2 = -0.5f * L2E * invd * invd;
            const float m2 = mean0[k] * mean0[k] + mean1[k] * mean1[k]
                           + mean2[k] * mean2[k];
            A[k] = a2;
            B[k] = a2 * m2;
            cc[k] = weight[k] * invd;
        }

        float rs[KC], mx[KC], my[KC], mz[KC], ac2[KC];
#pragma unroll
        for (int k = 0; k < KC; ++k) { rs[k] = mx[k] = my[k] = mz[k] = ac2[k] = 0.0f; }

#pragma unroll
        for (int j = 0; j < 4; ++j) {
            float r[KC], s = 0.0f;
#pragma unroll
            for (int k = 0; k < KC; ++k) {
                const float td = mean0[k] * x0[j] + mean1[k] * x1[j] + mean2[k] * x2[j];
                const float u = q[j] - 2.0f * td;
                const float e = A[k] * u + B[k];
                r[k] = cc[k] * fexp2(e);
                s += r[k];
            }
            const float sinv = (s > S_FLOOR) ? frcp(s) : 0.0f;
#pragma unroll
            for (int k = 0; k < KC; ++k) {
                const float rk = r[k] * sinv;
                rs[k]  += rk;
                mx[k]  += rk * x0[j];
                my[k]  += rk * x1[j];
                mz[k]  += rk * x2[j];
                ac2[k] += rk * q[j];
            }
        }

        // cross-lane pair reduction: both lanes end with the full 8-sample sums
#pragma unroll
        for (int k = 0; k < KC; ++k) {
            rs[k]  = dpp_pair_sum(rs[k]);
            mx[k]  = dpp_pair_sum(mx[k]);
            my[k]  = dpp_pair_sum(my[k]);
            mz[k]  = dpp_pair_sum(mz[k]);
            ac2[k] = dpp_pair_sum(ac2[k]);
        }

        // M-step finalize (computed redundantly but identically on both lanes)
#pragma unroll
        for (int k = 0; k < KC; ++k) {
            const float invrs = frcp(rs[k]);          // garbage if starved; selected away
            const float nm0 = mx[k] * invrs, nm1 = my[k] * invrs, nm2 = mz[k] * invrs;
            const float mm2 = nm0 * nm0 + nm1 * nm1 + nm2 * nm2;
            const float ndev = ac2[k] * invrs - mm2;  // Koenig identity
            const bool ok = rs[k] > S_FLOOR;
            mean0[k] = ok ? nm0 : mean0[k];
            mean1[k] = ok ? nm1 : mean1[k];
            mean2[k] = ok ? nm2 : mean2[k];
            dev[k]   = ok ? ndev : dev[k];
            weight[k] = rs[k] * 0.125f;               // rs/N — reference semantics
        }
    }

    // ---- fg ratio ----
    float ratio[KC];
    float rmin = 3.402823466e+38f;
#pragma unroll
    for (int k = 0; k < KC; ++k) {
        ratio[k] = weight[k] * frcp(fmaxf(dev[k], DEV_FLOOR));
        rmin = fminf(rmin, ratio[k]);
    }

    // ---- process the single test frame ----
    const float* fr = frame + (size_t)p * 3;
    const float fx = fr[0], fy = fr[1], fz = fr[2];

    float mind = 3.402823466e+38f;
    int index = 0;
#pragma unroll
    for (int k = 0; k < KC; ++k) {
        const float dx = fx - mean0[k];
        const float dy = fy - mean1[k];
        const float dz = fz - mean2[k];
        const float dist = __builtin_amdgcn_sqrtf(dx * dx + dy * dy + dz * dz);
        if (dist < mind) { mind = dist; index = k; }  // first-min (jnp.argmin)
    }

    const float mask = (ratio[index] <= rmin) ? 255.0f : 0.0f;
    const float md = isfinite(mind) ? mind : 0.0f;

    // parity store: even lane -> mask plane, odd lane -> min_dist plane
    out[(size_t)h * HWPIX + p] = h ? md : mask;
}

extern "C" void kernel_launch(void* const* d_in, const int* in_sizes, int n_in,
                              void* d_out, int out_size, void* d_ws, size_t ws_size,
                              hipStream_t stream) {
    const float* frames = (const float*)d_in[0];
    const float* frame  = (const float*)d_in[1];
    const int*   n_iter = (const int*)d_in[2];
    float* out = (float*)d_out;

    const int threads = 64;
    const int blocks = (HWPIX * 2) / threads;   // 9600 full waves
    gmm_fit_process_kernel<<<blocks, threads, 0, stream>>>(frames, frame, n_iter, out);
}

// Round 9
// 24.012 us; speedup vs baseline: 3.0789x; 1.3780x over previous
//
#include <hip/hip_runtime.h>
#include <math.h>

#define KC 3
#define NF 8
#define HH 480
#define WW 640
#define HWPIX (HH * WW)
#define FSTRIDE (HWPIX * 3)   // floats per frame plane

__device__ __forceinline__ float frcp(float x)  { return __builtin_amdgcn_rcpf(x); }
__device__ __forceinline__ float fexp2(float x) { return __builtin_amdgcn_exp2f(x); }
__device__ __forceinline__ float flog2(float x) { return __builtin_amdgcn_logf(x); }
__device__ __forceinline__ float fsqrtf(float x){ return __builtin_amdgcn_sqrtf(x); }
__device__ __forceinline__ float ffma(float a, float b, float c) { return __builtin_fmaf(a, b, c); }

struct Gmm {
    float m0[KC], m1[KC], m2[KC], dv[KC], wt[KC];
};

// One EM iteration. All arrays fully unrolled -> registers.
__device__ __forceinline__ void em_iter(const float (&x0)[NF], const float (&x1)[NF],
                                        const float (&x2)[NF], const float (&q)[NF],
                                        Gmm& g)
{
    const float L2E = 1.4426950408889634f;   // log2(e)
    const float DEV_FLOOR = 1e-12f;
    const float S_FLOOR = 1e-20f;

    // per-component constants: e_k(n) = A_k*(q - 2*dot) + B2_k
    //   A_k = -0.5*log2(e)/dev_k ; B2_k = A_k*||m_k||^2 + log2(w_k*invd_k)
    float A[KC], B2[KC];
#pragma unroll
    for (int k = 0; k < KC; ++k) {
        const float invd = frcp(fmaxf(g.dv[k], DEV_FLOOR));
        const float a2 = (-0.5f * L2E) * invd * invd;
        const float mm = ffma(g.m0[k], g.m0[k], ffma(g.m1[k], g.m1[k], g.m2[k] * g.m2[k]));
        const float lg = flog2(g.wt[k] * invd);  // w=0 -> -inf -> r=0 (finite path)
        A[k] = a2;
        B2[k] = ffma(a2, mm, lg);
    }

    float rs[KC], mx[KC], my[KC], mz[KC], aq[KC];
#pragma unroll
    for (int k = 0; k < KC; ++k) { rs[k] = mx[k] = my[k] = mz[k] = aq[k] = 0.0f; }

#pragma unroll
    for (int n = 0; n < NF; ++n) {
        const float xa = x0[n], xb = x1[n], xc = x2[n], qq = q[n];
        float r[KC];
#pragma unroll
        for (int k = 0; k < KC; ++k) {
            const float t = ffma(g.m0[k], xa, ffma(g.m1[k], xb, g.m2[k] * xc));
            const float u = ffma(-2.0f, t, qq);
            r[k] = fexp2(ffma(A[k], u, B2[k]));
        }
        const float s = r[0] + r[1] + r[2];
        const float sinv = (s > S_FLOOR) ? frcp(s) : 0.0f;
#pragma unroll
        for (int k = 0; k < KC; ++k) {
            const float rk = r[k] * sinv;
            rs[k] += rk;
            mx[k] = ffma(rk, xa, mx[k]);
            my[k] = ffma(rk, xb, my[k]);
            mz[k] = ffma(rk, xc, mz[k]);
            aq[k] = ffma(rk, qq, aq[k]);
        }
    }

#pragma unroll
    for (int k = 0; k < KC; ++k) {
        const float invrs = frcp(rs[k]);          // garbage if starved; selected away
        const float n0 = mx[k] * invrs, n1 = my[k] * invrs, n2 = mz[k] * invrs;
        const float mm2 = ffma(n0, n0, ffma(n1, n1, n2 * n2));
        const float nd = ffma(aq[k], invrs, -mm2);  // Koenig identity
        const bool ok = rs[k] > S_FLOOR;
        g.m0[k] = ok ? n0 : g.m0[k];
        g.m1[k] = ok ? n1 : g.m1[k];
        g.m2[k] = ok ? n2 : g.m2[k];
        g.dv[k] = ok ? nd : g.dv[k];
        g.wt[k] = rs[k] * 0.125f;                 // rs/N — reference semantics
    }
}

__global__ __launch_bounds__(64, 4) void gmm_fit_process_kernel(
    const float* __restrict__ frames,   // [N,H,W,3]
    const float* __restrict__ frame,    // [H,W,3]
    const int* __restrict__ n_iter_p,
    float* __restrict__ out)            // [2,H,W]
{
    const int p = blockIdx.x * 64 + threadIdx.x;   // one pixel per thread
    if (p >= HWPIX) return;
    const int n_iter = *n_iter_p;

    // ---- load all 8 samples once into registers ----
    float x0[NF], x1[NF], x2[NF], q[NF];
    {
        const float* base = frames + (size_t)p * 3;
#pragma unroll
        for (int n = 0; n < NF; ++n) {
            const float* s = base + (size_t)n * FSTRIDE;
            x0[n] = s[0]; x1[n] = s[1]; x2[n] = s[2];
            q[n] = ffma(x0[n], x0[n], ffma(x1[n], x1[n], x2[n] * x2[n]));
        }
    }

    // ---- init GMM state ----
    Gmm g;
#pragma unroll
    for (int k = 0; k < KC; ++k) {
        const float m0 = (float)(k + 1) / 4.0f;
        g.m0[k] = m0; g.m1[k] = m0; g.m2[k] = m0;
        g.dv[k] = 1.0f;
        g.wt[k] = 1.0f / 3.0f;
    }

    // fully-unrolled hot path for the actual n_iter=5 input; generic fallback
    if (n_iter == 5) {
#pragma unroll
        for (int it = 0; it < 5; ++it) em_iter(x0, x1, x2, q, g);
    } else {
        for (int it = 0; it < n_iter; ++it) em_iter(x0, x1, x2, q, g);
    }

    // ---- fg ratio ----
    const float DEV_FLOOR = 1e-12f;
    float ratio[KC];
    float rmin = 3.402823466e+38f;
#pragma unroll
    for (int k = 0; k < KC; ++k) {
        ratio[k] = g.wt[k] * frcp(fmaxf(g.dv[k], DEV_FLOOR));
        rmin = fminf(rmin, ratio[k]);
    }

    // ---- process the single test frame ----
    const float* fr = frame + (size_t)p * 3;
    const float fx = fr[0], fy = fr[1], fz = fr[2];

    float mind = 3.402823466e+38f;
    int index = 0;
#pragma unroll
    for (int k = 0; k < KC; ++k) {
        const float dx = fx - g.m0[k];
        const float dy = fy - g.m1[k];
        const float dz = fz - g.m2[k];
        const float dist = fsqrtf(ffma(dx, dx, ffma(dy, dy, dz * dz)));
        if (dist < mind) { mind = dist; index = k; }  // first-min (jnp.argmin)
    }

    const float mask = (ratio[index] <= rmin) ? 255.0f : 0.0f;
    out[p] = mask;
    out[HWPIX + p] = isfinite(mind) ? mind : 0.0f;
}

extern "C" void kernel_launch(void* const* d_in, const int* in_sizes, int n_in,
                              void* d_out, int out_size, void* d_ws, size_t ws_size,
                              hipStream_t stream) {
    const float* frames = (const float*)d_in[0];
    const float* frame  = (const float*)d_in[1];
    const int*   n_iter = (const int*)d_in[2];
    float* out = (float*)d_out;

    const int threads = 64;
    const int blocks = (HWPIX + threads - 1) / threads;  // 4800 waves
    gmm_fit_process_kernel<<<blocks, threads, 0, stream>>>(frames, frame, n_iter, out);
}